// Round 4
// baseline (278.653 us; speedup 1.0000x reference)
//
#include <hip/hip_runtime.h>
#include <hip/hip_bf16.h>
#include <cstdint>

// PredictiveColumn: B=16384, DIN=DOUT=512, K_WTA=128, LATERAL_K=3
// prep_k : bf16 W^T, W, V^T ; lateral band Mc7[7][512]; zero ssq
// kwta_k : 1 wave/row top-128 via ballot binary search with exact-count early
//          exit; fast-poly gelu/gelu'; base = b_in+3td-4x+0.3*lat-1e-6*sign
// gemm_k<1>: err = bf16(bu - (phi@W + b_out))
// gemm_k<2>: fb  = bf16((err@W^T) * pd)
// gemm_k<3>: d16 = bf16(tau*eta*((bu@V) + fb + base)), ssq += d^2
// final_k: out = clamp(x + d16*min(1,1/(||d||+1e-8)), -5, 5)

#define DEV static __device__ __forceinline__

typedef __attribute__((ext_vector_type(8))) short short8;   // 8 bf16 (4 VGPRs)
typedef __attribute__((ext_vector_type(4))) float f32x4;

static constexpr int BATCH = 16384;
static constexpr int D = 512;

DEV unsigned short f2bf(float f) {           // RNE float->bf16 (no NaN inputs here)
  unsigned u = __float_as_uint(f);
  return (unsigned short)((u + 0x7FFFu + ((u >> 16) & 1u)) >> 16);
}
DEV float bf2f(unsigned short h) { return __uint_as_float(((unsigned)h) << 16); }

DEV float wsumf(float v) { for (int o = 32; o; o >>= 1) v += __shfl_xor(v, o, 64); return v; }

DEV void gload16(const void* g, void* l) {
  __builtin_amdgcn_global_load_lds((const __attribute__((address_space(1))) void*)g,
                                   (__attribute__((address_space(3))) void*)l, 16, 0, 0);
}

DEV void load8(const float* rowp, int lane, float v[8]) {
  const float4* q = (const float4*)rowp;
  float4 a = q[lane * 2], b = q[lane * 2 + 1];
  v[0] = a.x; v[1] = a.y; v[2] = a.z; v[3] = a.w;
  v[4] = b.x; v[5] = b.y; v[6] = b.z; v[7] = b.w;
}

// ---------------------------------------------------------------- prep
__global__ __launch_bounds__(256) void prep_k(
    const float* __restrict__ W, const float* __restrict__ V,
    const float* __restrict__ L, const float* __restrict__ Lm,
    unsigned short* __restrict__ Wbt, unsigned short* __restrict__ Wb2,
    unsigned short* __restrict__ Vbt, float* __restrict__ Mc7,
    float* __restrict__ ssq)
{
  int idx = blockIdx.x * 256 + threadIdx.x;      // 0 .. 512*512-1
  int n = idx >> 9, k = idx & 511;
  Wbt[idx] = f2bf(W[k * D + n]);                 // G1 B^T:  Wbt[n][k] = W[k][n]
  Wb2[idx] = f2bf(W[idx]);                       // G2 B^T:  W[n][k] as-is
  Vbt[idx] = f2bf(V[k * D + n]);                 // G3 B^T:  V[k][n]
  if (idx < 7 * D) {                             // lateral band, layout [t][n]
    int t = idx >> 9, nn = idx & 511;
    int j = nn - 3 + t;
    float v = 0.f;
    if (j >= 0 && j < D && j != nn) v = L[j * D + nn] * Lm[j * D + nn];
    Mc7[idx] = v;
  }
  if (idx == 0) *ssq = 0.f;
}

// ---------------------------------------------------------------- kwta + phi + base
__global__ __launch_bounds__(256) void kwta_k(
    const float* __restrict__ x, const float* __restrict__ td,
    const float* __restrict__ bu, const float* __restrict__ b_in,
    const float* __restrict__ Mc7,
    unsigned short* __restrict__ phi16, unsigned short* __restrict__ pd16,
    unsigned short* __restrict__ base16, unsigned short* __restrict__ bu16)
{
  __shared__ float pbuf[4][D];                    // layout [(n&7)][n>>3] : bank-safe
  const int tid = threadIdx.x, lane = tid & 63, wv = tid >> 6;
  const int row = blockIdx.x * 4 + wv;
  const size_t rbase = (size_t)row * D;

  float xv[8];
  load8(x + rbase, lane, xv);
  unsigned key[8];
  #pragma unroll
  for (int s = 0; s < 8; ++s) {                   // order-preserving uint keys
    unsigned u = __float_as_uint(xv[s]);
    key[s] = (u & 0x80000000u) ? ~u : (u | 0x80000000u);
  }
  // threshold key T: max T with count(key>=T) >= 128. Early exit when the
  // count hits 128 exactly: then {key>=T} IS the top-128 (all ties included).
  unsigned T = 0u;
  bool exact = false;
  for (int bit = 31; bit >= 0; --bit) {
    unsigned cand = T | (1u << bit);
    int c = 0;
    #pragma unroll
    for (int s = 0; s < 8; ++s) c += (int)__popcll(__ballot(key[s] >= cand));
    if (c == 128) { T = cand; exact = true; break; }
    if (c > 128) T = cand;
  }

  bool selv[8];
  if (exact) {
    #pragma unroll
    for (int s = 0; s < 8; ++s) selv[s] = (key[s] >= T);
  } else {                                        // tie-break: lowest index first
    int cg = 0;
    unsigned long long em[8];
    #pragma unroll
    for (int s = 0; s < 8; ++s) {
      cg += (int)__popcll(__ballot(key[s] > T));
      em[s] = __ballot(key[s] == T);
    }
    const int rneed = 128 - cg;
    const unsigned long long lower = (1ull << lane) - 1ull;
    int run = 0;
    #pragma unroll
    for (int s = 0; s < 8; ++s) run += (int)__popcll(em[s] & lower);
    #pragma unroll
    for (int s = 0; s < 8; ++s) {
      bool sel = key[s] > T;
      if (key[s] == T) { sel = (run < rneed); ++run; }
      selv[s] = sel;
    }
  }

  float phiv[8], pdv[8];
  float* pb = pbuf[wv];
  #pragma unroll
  for (int s = 0; s < 8; ++s) {
    float v = xv[s];
    // erf(z), z=v/sqrt(2) via A&S 7.1.26 (|err|<1.5e-7), reusing e=exp(-v*v/2)
    float e  = __expf(-0.5f * v * v);
    float az = fabsf(v) * 0.7071067811865476f;
    float t  = __builtin_amdgcn_rcpf(1.0f + 0.3275911f * az);
    float p  = 0.254829592f + t * (-0.284496736f + t * (1.421413741f +
               t * (-1.453152027f + t * 1.061405429f)));
    float erfa = 1.0f - p * t * e;                // erf(|z|)
    float erfs = (v < 0.f) ? -erfa : erfa;
    float cdf = 0.5f * (1.0f + erfs);
    float ph = selv[s] ? v * cdf : 0.0f;
    float pd = selv[s] ? (cdf + v * 0.3989422804014327f * e) : 0.0f;
    phiv[s] = ph; pdv[s] = pd;
    pb[(s << 6) | lane] = ph;                     // [(n&7)][n>>3]
  }
  __syncthreads();                                // phi row visible for lateral reads

  float tdv[8], buv[8];
  load8(td + rbase, lane, tdv);
  load8(bu + rbase, lane, buv);

  float lat[8] = {0.f, 0.f, 0.f, 0.f, 0.f, 0.f, 0.f, 0.f};
  #pragma unroll
  for (int t = 0; t < 7; ++t) {                   // 14 coalesced float4 coeff loads
    const float4* mq = (const float4*)(Mc7 + t * D + lane * 8);
    float4 m0 = mq[0], m1 = mq[1];
    float mm[8] = {m0.x, m0.y, m0.z, m0.w, m1.x, m1.y, m1.z, m1.w};
    #pragma unroll
    for (int s = 0; s < 8; ++s) {
      int j = lane * 8 + s - 3 + t;
      int jc = j < 0 ? 0 : (j > D - 1 ? D - 1 : j);   // Mc7==0 at OOB, clamp safe
      lat[s] += mm[s] * pb[((jc & 7) << 6) | (jc >> 3)];
    }
  }

  short8 o_phi, o_pd, o_base, o_bu;
  #pragma unroll
  for (int s = 0; s < 8; ++s) {
    int n = lane * 8 + s;
    float v = xv[s];
    float sgn = (v > 0.f) ? 1.f : ((v < 0.f) ? -1.f : 0.f);
    float bs = b_in[n] + 3.f * tdv[s] - 4.f * v + 0.3f * lat[s] - 1e-6f * sgn;
    o_phi[s] = (short)f2bf(phiv[s]);
    o_pd[s]  = (short)f2bf(pdv[s]);
    o_base[s]= (short)f2bf(bs);
    o_bu[s]  = (short)f2bf(buv[s]);
  }
  *(short8*)(phi16 + rbase + lane * 8) = o_phi;
  *(short8*)(pd16  + rbase + lane * 8) = o_pd;
  *(short8*)(base16+ rbase + lane * 8) = o_base;
  *(short8*)(bu16  + rbase + lane * 8) = o_bu;
}

// ---------------------------------------------------------------- GEMM
// C[b,n] = sum_k A[b,k]*Bt[n,k]; 128x128 tile, BK=32, double-buffered LDS,
// one barrier per K-step (T3-minimal prefetch), XCD-chunked block swizzle.
template<int MODE>
__global__ __launch_bounds__(256) void gemm_k(
    const unsigned short* __restrict__ A,    // [16384][512] bf16
    const unsigned short* __restrict__ Bt,   // [512][512] bf16 (pre-transposed)
    const float* __restrict__ f32b,          // M1: b_out_snap
    const unsigned short* __restrict__ b16a, // M1: bu16 ; M2: pd16 ; M3: fb16
    const unsigned short* __restrict__ b16b, // M3: base16
    unsigned short* __restrict__ out16,      // M1: err16 ; M2: fb16 ; M3: d16
    float* __restrict__ ssq,                 // M3
    const int* __restrict__ stepi)           // M3
{
  constexpr int K = 512;
  constexpr int NT = K / 32;
  __shared__ __align__(16) unsigned short As[2][128 * 32];
  __shared__ __align__(16) unsigned short Bs[2][128 * 32];
  const int tid = threadIdx.x;
  const int lane = tid & 63, w = tid >> 6;
  const int lid = (blockIdx.x & 7) * 64 + (blockIdx.x >> 3);  // XCD chunk swizzle
  const int m0 = (lid >> 2) * 128, n0 = (lid & 3) * 128;
  const int qr = (w >> 1) * 64, qc = (w & 1) * 64;
  const int lr = lane & 15, g = lane >> 4;

  f32x4 acc[4][4];
  #pragma unroll
  for (int m = 0; m < 4; ++m)
    #pragma unroll
    for (int n = 0; n < 4; ++n) acc[m][n] = (f32x4){0.f, 0.f, 0.f, 0.f};

  const unsigned short* Abase = A + (size_t)m0 * K;
  const unsigned short* Bbase = Bt + (size_t)n0 * K;

  const int ch0 = tid, ch1 = tid + 256;           // 16B chunk ids
  const int r0 = ch0 >> 2, c0 = (ch0 & 3) * 8;
  const int r1 = ch1 >> 2, c1 = (ch1 & 3) * 8;
  auto stage = [&](int buf, int kt) {
    gload16(Abase + r0 * K + kt + c0, As[buf] + (size_t)(w * 64) * 8);
    gload16(Bbase + r0 * K + kt + c0, Bs[buf] + (size_t)(w * 64) * 8);
    gload16(Abase + r1 * K + kt + c1, As[buf] + (size_t)(w * 64 + 256) * 8);
    gload16(Bbase + r1 * K + kt + c1, Bs[buf] + (size_t)(w * 64 + 256) * 8);
  };

  stage(0, 0);
  __syncthreads();                                // drains vmcnt(0)
  #pragma unroll
  for (int kt = 0; kt < NT; ++kt) {
    const int cur = kt & 1;
    if (kt + 1 < NT) stage(cur ^ 1, (kt + 1) * 32);  // prefetch next K-step
    short8 af[4], bfr[4];
    #pragma unroll
    for (int m = 0; m < 4; ++m) af[m]  = *(const short8*)(As[cur] + (qr + 16 * m + lr) * 32 + 8 * g);
    #pragma unroll
    for (int n = 0; n < 4; ++n) bfr[n] = *(const short8*)(Bs[cur] + (qc + 16 * n + lr) * 32 + 8 * g);
    #pragma unroll
    for (int m = 0; m < 4; ++m)
      #pragma unroll
      for (int n = 0; n < 4; ++n)
        acc[m][n] = __builtin_amdgcn_mfma_f32_16x16x32_bf16(af[m], bfr[n], acc[m][n], 0, 0, 0);
    __syncthreads();                              // drain prefetch + protect cur buf
  }

  float tau_eta = 0.f, lssq = 0.f;
  if constexpr (MODE == 3) tau_eta = 0.5f * 0.8f / (1.0f + 0.1f * (float)stepi[0]);
  #pragma unroll
  for (int m = 0; m < 4; ++m) {
    #pragma unroll
    for (int n = 0; n < 4; ++n) {
      #pragma unroll
      for (int r = 0; r < 4; ++r) {
        int row = m0 + qr + 16 * m + 4 * g + r;   // C/D: col=lane&15, row=4*(lane>>4)+reg
        int col = n0 + qc + 16 * n + lr;
        size_t idx = (size_t)row * D + col;
        float v = acc[m][n][r];
        if constexpr (MODE == 1) {
          out16[idx] = f2bf(bf2f(b16a[idx]) - (v + f32b[col]));
        } else if constexpr (MODE == 2) {
          out16[idx] = f2bf(v * bf2f(b16a[idx]));
        } else {
          float dv = tau_eta * (v + bf2f(b16a[idx]) + bf2f(b16b[idx]));
          out16[idx] = f2bf(dv);
          lssq += dv * dv;
        }
      }
    }
  }
  if constexpr (MODE == 3) {
    lssq = wsumf(lssq);
    if (lane == 0) atomicAdd(ssq, lssq);
  }
}

// ---------------------------------------------------------------- final scale+clamp
__global__ __launch_bounds__(256) void final_k(const float* __restrict__ x,
                                               const unsigned short* __restrict__ d16,
                                               float* __restrict__ out,
                                               const float* __restrict__ ssq)
{
  float nrm = sqrtf(*ssq);
  float s = nrm > 1.0f ? 1.0f / (nrm + 1e-8f) : 1.0f;
  size_t i = (size_t)blockIdx.x * 256 + threadIdx.x;   // 8 elems/thread
  short8 dv = *(const short8*)(d16 + i * 8);
  const float4* xq = (const float4*)(x + i * 8);
  float4 xa = xq[0], xb = xq[1];
  float4 oa, ob;
  oa.x = fminf(fmaxf(xa.x + s * bf2f((unsigned short)dv[0]), -5.f), 5.f);
  oa.y = fminf(fmaxf(xa.y + s * bf2f((unsigned short)dv[1]), -5.f), 5.f);
  oa.z = fminf(fmaxf(xa.z + s * bf2f((unsigned short)dv[2]), -5.f), 5.f);
  oa.w = fminf(fmaxf(xa.w + s * bf2f((unsigned short)dv[3]), -5.f), 5.f);
  ob.x = fminf(fmaxf(xb.x + s * bf2f((unsigned short)dv[4]), -5.f), 5.f);
  ob.y = fminf(fmaxf(xb.y + s * bf2f((unsigned short)dv[5]), -5.f), 5.f);
  ob.z = fminf(fmaxf(xb.z + s * bf2f((unsigned short)dv[6]), -5.f), 5.f);
  ob.w = fminf(fmaxf(xb.w + s * bf2f((unsigned short)dv[7]), -5.f), 5.f);
  float4* oq = (float4*)(out + i * 8);
  oq[0] = oa; oq[1] = ob;
}

// ---------------------------------------------------------------- launch
extern "C" void kernel_launch(void* const* d_in, const int* in_sizes, int n_in,
                              void* d_out, int out_size, void* d_ws, size_t ws_size,
                              hipStream_t stream) {
  const float* bu    = (const float*)d_in[0];
  const float* td    = (const float*)d_in[1];
  const float* x     = (const float*)d_in[2];
  const float* V     = (const float*)d_in[3];
  const float* b_in  = (const float*)d_in[4];
  const float* W     = (const float*)d_in[5];
  const float* bout  = (const float*)d_in[6];
  const float* L     = (const float*)d_in[7];
  const float* Lm    = (const float*)d_in[8];
  const int*   stepi = (const int*)d_in[9];
  float* dout = (float*)d_out;

  char* p = (char*)d_ws;
  size_t off = 0;
  auto take = [&](size_t bytes) -> void* {
    void* r = (void*)(p + off);
    off += (bytes + 255) & ~(size_t)255;
    return r;
  };
  float* ssq            = (float*)take(4);
  unsigned short* Wbt   = (unsigned short*)take((size_t)D * D * 2);
  unsigned short* Wb2   = (unsigned short*)take((size_t)D * D * 2);
  unsigned short* Vbt   = (unsigned short*)take((size_t)D * D * 2);
  float* Mc7            = (float*)take((size_t)7 * D * 4);
  const size_t bd = (size_t)BATCH * D * 2;
  unsigned short* phi16 = (unsigned short*)take(bd);
  unsigned short* bu16  = (unsigned short*)take(bd);
  unsigned short* pd16  = (unsigned short*)take(bd);
  unsigned short* bse16 = (unsigned short*)take(bd);
  unsigned short* err16 = (unsigned short*)take(bd);
  unsigned short* fb16  = phi16;   // phi dead after G1; reuse for fb
  unsigned short* d16   = err16;   // err dead after G2; reuse for d

  prep_k<<<(D * D) / 256, 256, 0, stream>>>(W, V, L, Lm, Wbt, Wb2, Vbt, Mc7, ssq);
  kwta_k<<<BATCH / 4, 256, 0, stream>>>(x, td, bu, b_in, Mc7, phi16, pd16, bse16, bu16);
  gemm_k<1><<<(BATCH / 128) * (D / 128), 256, 0, stream>>>(
      phi16, Wbt, bout, bu16, nullptr, err16, nullptr, nullptr);
  gemm_k<2><<<(BATCH / 128) * (D / 128), 256, 0, stream>>>(
      err16, Wb2, nullptr, pd16, nullptr, fb16, nullptr, nullptr);
  gemm_k<3><<<(BATCH / 128) * (D / 128), 256, 0, stream>>>(
      bu16, Vbt, nullptr, fb16, bse16, d16, ssq, stepi);
  final_k<<<BATCH * D / 8 / 256, 256, 0, stream>>>(x, d16, dout, ssq);
}

// Round 6
// 252.124 us; speedup vs baseline: 1.1052x; 1.1052x over previous
//
#include <hip/hip_runtime.h>
#include <hip/hip_bf16.h>
#include <cstdint>

// PredictiveColumn: B=16384, DIN=DOUT=512, K_WTA=128, LATERAL_K=3
// prep_k : bf16 W^T, W, V^T ; lateral band Mc7[7][512]; zero ssq
// kwta_k : 1 wave/row top-128 via ballot binary search with exact-count early
//          exit; fast-poly gelu/gelu'; base = b_in+3td-4x+0.3*lat-1e-6*sign
// gemm_k<1>: err = bf16(bu - (phi@W + b_out))
// gemm_k<2>: fb  = bf16((err@W^T) * pd)
// gemm_k<3>: d16 = bf16(tau*eta*((bu@V) + fb + base)), ssq += d^2
// final_k: out = clamp(x + d16*min(1,1/(||d||+1e-8)), -5, 5)
//
// GEMM pipeline (R5): ring-4 LDS buffers, 2-tile-ahead global_load_lds
// prefetch, ONE raw s_barrier per K-step, counted s_waitcnt vmcnt(8)
// (never 0 in steady state) so prefetch loads stay in flight across the
// barrier — the R3/R4 __syncthreads() version drained vmcnt(0) every step
// (MfmaUtil 5%, all pipes idle).

#define DEV static __device__ __forceinline__

typedef __attribute__((ext_vector_type(8))) short short8;   // 8 bf16 (4 VGPRs)
typedef __attribute__((ext_vector_type(4))) float f32x4;

static constexpr int BATCH = 16384;
static constexpr int D = 512;

DEV unsigned short f2bf(float f) {           // RNE float->bf16 (no NaN inputs here)
  unsigned u = __float_as_uint(f);
  return (unsigned short)((u + 0x7FFFu + ((u >> 16) & 1u)) >> 16);
}
DEV float bf2f(unsigned short h) { return __uint_as_float(((unsigned)h) << 16); }

DEV float wsumf(float v) { for (int o = 32; o; o >>= 1) v += __shfl_xor(v, o, 64); return v; }

DEV void gload16(const void* g, void* l) {
  __builtin_amdgcn_global_load_lds((const __attribute__((address_space(1))) void*)g,
                                   (__attribute__((address_space(3))) void*)l, 16, 0, 0);
}

DEV void load8(const float* rowp, int lane, float v[8]) {
  const float4* q = (const float4*)rowp;
  float4 a = q[lane * 2], b = q[lane * 2 + 1];
  v[0] = a.x; v[1] = a.y; v[2] = a.z; v[3] = a.w;
  v[4] = b.x; v[5] = b.y; v[6] = b.z; v[7] = b.w;
}

// ---------------------------------------------------------------- prep
__global__ __launch_bounds__(256) void prep_k(
    const float* __restrict__ W, const float* __restrict__ V,
    const float* __restrict__ L, const float* __restrict__ Lm,
    unsigned short* __restrict__ Wbt, unsigned short* __restrict__ Wb2,
    unsigned short* __restrict__ Vbt, float* __restrict__ Mc7,
    float* __restrict__ ssq)
{
  int idx = blockIdx.x * 256 + threadIdx.x;      // 0 .. 512*512-1
  int n = idx >> 9, k = idx & 511;
  Wbt[idx] = f2bf(W[k * D + n]);                 // G1 B^T:  Wbt[n][k] = W[k][n]
  Wb2[idx] = f2bf(W[idx]);                       // G2 B^T:  W[n][k] as-is
  Vbt[idx] = f2bf(V[k * D + n]);                 // G3 B^T:  V[k][n]
  if (idx < 7 * D) {                             // lateral band, layout [t][n]
    int t = idx >> 9, nn = idx & 511;
    int j = nn - 3 + t;
    float v = 0.f;
    if (j >= 0 && j < D && j != nn) v = L[j * D + nn] * Lm[j * D + nn];
    Mc7[idx] = v;
  }
  if (idx == 0) *ssq = 0.f;
}

// ---------------------------------------------------------------- kwta + phi + base
__global__ __launch_bounds__(256) void kwta_k(
    const float* __restrict__ x, const float* __restrict__ td,
    const float* __restrict__ bu, const float* __restrict__ b_in,
    const float* __restrict__ Mc7,
    unsigned short* __restrict__ phi16, unsigned short* __restrict__ pd16,
    unsigned short* __restrict__ base16, unsigned short* __restrict__ bu16)
{
  __shared__ float pbuf[4][D];                    // layout [(n&7)][n>>3] : bank-safe
  const int tid = threadIdx.x, lane = tid & 63, wv = tid >> 6;
  const int row = blockIdx.x * 4 + wv;
  const size_t rbase = (size_t)row * D;

  float xv[8];
  load8(x + rbase, lane, xv);
  unsigned key[8];
  #pragma unroll
  for (int s = 0; s < 8; ++s) {                   // order-preserving uint keys
    unsigned u = __float_as_uint(xv[s]);
    key[s] = (u & 0x80000000u) ? ~u : (u | 0x80000000u);
  }
  // threshold key T: max T with count(key>=T) >= 128. Early exit when the
  // count hits 128 exactly: then {key>=T} IS the top-128 (all ties included).
  unsigned T = 0u;
  bool exact = false;
  for (int bit = 31; bit >= 0; --bit) {
    unsigned cand = T | (1u << bit);
    int c = 0;
    #pragma unroll
    for (int s = 0; s < 8; ++s) c += (int)__popcll(__ballot(key[s] >= cand));
    if (c == 128) { T = cand; exact = true; break; }
    if (c > 128) T = cand;
  }

  bool selv[8];
  if (exact) {
    #pragma unroll
    for (int s = 0; s < 8; ++s) selv[s] = (key[s] >= T);
  } else {                                        // tie-break: lowest index first
    int cg = 0;
    unsigned long long em[8];
    #pragma unroll
    for (int s = 0; s < 8; ++s) {
      cg += (int)__popcll(__ballot(key[s] > T));
      em[s] = __ballot(key[s] == T);
    }
    const int rneed = 128 - cg;
    const unsigned long long lower = (1ull << lane) - 1ull;
    int run = 0;
    #pragma unroll
    for (int s = 0; s < 8; ++s) run += (int)__popcll(em[s] & lower);
    #pragma unroll
    for (int s = 0; s < 8; ++s) {
      bool sel = key[s] > T;
      if (key[s] == T) { sel = (run < rneed); ++run; }
      selv[s] = sel;
    }
  }

  float phiv[8], pdv[8];
  float* pb = pbuf[wv];
  #pragma unroll
  for (int s = 0; s < 8; ++s) {
    float v = xv[s];
    // erf(z), z=v/sqrt(2) via A&S 7.1.26 (|err|<1.5e-7), reusing e=exp(-v*v/2)
    float e  = __expf(-0.5f * v * v);
    float az = fabsf(v) * 0.7071067811865476f;
    float t  = __builtin_amdgcn_rcpf(1.0f + 0.3275911f * az);
    float p  = 0.254829592f + t * (-0.284496736f + t * (1.421413741f +
               t * (-1.453152027f + t * 1.061405429f)));
    float erfa = 1.0f - p * t * e;                // erf(|z|)
    float erfs = (v < 0.f) ? -erfa : erfa;
    float cdf = 0.5f * (1.0f + erfs);
    float ph = selv[s] ? v * cdf : 0.0f;
    float pd = selv[s] ? (cdf + v * 0.3989422804014327f * e) : 0.0f;
    phiv[s] = ph; pdv[s] = pd;
    pb[(s << 6) | lane] = ph;                     // [(n&7)][n>>3]
  }
  __syncthreads();                                // phi row visible for lateral reads

  float tdv[8], buv[8];
  load8(td + rbase, lane, tdv);
  load8(bu + rbase, lane, buv);

  float lat[8] = {0.f, 0.f, 0.f, 0.f, 0.f, 0.f, 0.f, 0.f};
  #pragma unroll
  for (int t = 0; t < 7; ++t) {                   // 14 coalesced float4 coeff loads
    const float4* mq = (const float4*)(Mc7 + t * D + lane * 8);
    float4 m0 = mq[0], m1 = mq[1];
    float mm[8] = {m0.x, m0.y, m0.z, m0.w, m1.x, m1.y, m1.z, m1.w};
    #pragma unroll
    for (int s = 0; s < 8; ++s) {
      int j = lane * 8 + s - 3 + t;
      int jc = j < 0 ? 0 : (j > D - 1 ? D - 1 : j);   // Mc7==0 at OOB, clamp safe
      lat[s] += mm[s] * pb[((jc & 7) << 6) | (jc >> 3)];
    }
  }

  short8 o_phi, o_pd, o_base, o_bu;
  #pragma unroll
  for (int s = 0; s < 8; ++s) {
    int n = lane * 8 + s;
    float v = xv[s];
    float sgn = (v > 0.f) ? 1.f : ((v < 0.f) ? -1.f : 0.f);
    float bs = b_in[n] + 3.f * tdv[s] - 4.f * v + 0.3f * lat[s] - 1e-6f * sgn;
    o_phi[s] = (short)f2bf(phiv[s]);
    o_pd[s]  = (short)f2bf(pdv[s]);
    o_base[s]= (short)f2bf(bs);
    o_bu[s]  = (short)f2bf(buv[s]);
  }
  *(short8*)(phi16 + rbase + lane * 8) = o_phi;
  *(short8*)(pd16  + rbase + lane * 8) = o_pd;
  *(short8*)(base16+ rbase + lane * 8) = o_base;
  *(short8*)(bu16  + rbase + lane * 8) = o_bu;
}

// ---------------------------------------------------------------- GEMM
// C[b,n] = sum_k A[b,k]*Bt[n,k]; 128x128 tile, BK=32, ring-4 LDS, 2-ahead
// prefetch, one raw barrier + counted vmcnt per K-step, XCD block swizzle.
template<int MODE>
__global__ __launch_bounds__(256) void gemm_k(
    const unsigned short* __restrict__ A,    // [16384][512] bf16
    const unsigned short* __restrict__ Bt,   // [512][512] bf16 (pre-transposed)
    const float* __restrict__ f32b,          // M1: b_out_snap
    const unsigned short* __restrict__ b16a, // M1: bu16 ; M2: pd16 ; M3: fb16
    const unsigned short* __restrict__ b16b, // M3: base16
    unsigned short* __restrict__ out16,      // M1: err16 ; M2: fb16 ; M3: d16
    float* __restrict__ ssq,                 // M3
    const int* __restrict__ stepi)           // M3
{
  constexpr int K = 512;
  constexpr int NT = K / 32;                      // 16 K-steps
  __shared__ __align__(16) unsigned short As[4][128 * 32];   // 32 KB ring
  __shared__ __align__(16) unsigned short Bs[4][128 * 32];   // 32 KB ring
  const int tid = threadIdx.x;
  const int lane = tid & 63, w = tid >> 6;
  const int lid = (blockIdx.x & 7) * 64 + (blockIdx.x >> 3);  // XCD chunk swizzle
  const int m0 = (lid >> 2) * 128, n0 = (lid & 3) * 128;
  const int qr = (w >> 1) * 64, qc = (w & 1) * 64;
  const int lr = lane & 15, g = lane >> 4;

  f32x4 acc[4][4];
  #pragma unroll
  for (int m = 0; m < 4; ++m)
    #pragma unroll
    for (int n = 0; n < 4; ++n) acc[m][n] = (f32x4){0.f, 0.f, 0.f, 0.f};

  const unsigned short* Abase = A + (size_t)m0 * K;
  const unsigned short* Bbase = Bt + (size_t)n0 * K;

  const int r0 = tid >> 2, c0 = (tid & 3) * 8;    // 16B chunk 0 (A and B)
  const int ch1 = tid + 256;
  const int r1 = ch1 >> 2, c1 = (ch1 & 3) * 8;    // 16B chunk 1

  // stage: 4 global_load_lds per thread; LDS dest = wave-uniform base,
  // HW adds lane*16B; linear layout matches [row][32] tile (ch*16B).
  auto stage = [&](int buf, int kt) {
    gload16(Abase + (size_t)r0 * K + kt + c0, As[buf] + (w * 64) * 8);
    gload16(Bbase + (size_t)r0 * K + kt + c0, Bs[buf] + (w * 64) * 8);
    gload16(Abase + (size_t)r1 * K + kt + c1, As[buf] + (w * 64 + 256) * 8);
    gload16(Bbase + (size_t)r1 * K + kt + c1, Bs[buf] + (w * 64 + 256) * 8);
  };
  auto compute = [&](int buf) {
    short8 af[4], bfr[4];
    #pragma unroll
    for (int m = 0; m < 4; ++m) af[m]  = *(const short8*)(As[buf] + (qr + 16 * m + lr) * 32 + 8 * g);
    #pragma unroll
    for (int n = 0; n < 4; ++n) bfr[n] = *(const short8*)(Bs[buf] + (qc + 16 * n + lr) * 32 + 8 * g);
    #pragma unroll
    for (int m = 0; m < 4; ++m)
      #pragma unroll
      for (int n = 0; n < 4; ++n)
        acc[m][n] = __builtin_amdgcn_mfma_f32_16x16x32_bf16(af[m], bfr[n], acc[m][n], 0, 0, 0);
  };

  stage(0, 0);
  stage(1, 32);                                   // 8 loads in flight
  #pragma unroll
  for (int t = 0; t < NT - 2; ++t) {
    stage((t + 2) & 3, (t + 2) * 32);             // +4 loads (tile t+2)
    // wait my tile-t loads only (t+1,t+2 stay in flight across the barrier);
    // barrier => every wave passed its own wait => tile t fully in LDS.
    asm volatile("s_waitcnt vmcnt(8)" ::: "memory");
    __builtin_amdgcn_s_barrier();
    compute(t & 3);
    // write-hazard audit: stage(t+2) writes buf[(t+2)&3]; slowest concurrent
    // wave is in iter t-1 reading buf[(t+3)&3]; buf[(t+2)&3]'s last readers
    // (iter t-2) finished before barrier t-1. Ring-4 + 1 barrier = race-free.
  }
  asm volatile("s_waitcnt vmcnt(4)" ::: "memory");
  __builtin_amdgcn_s_barrier();
  compute((NT - 2) & 3);
  asm volatile("s_waitcnt vmcnt(0)" ::: "memory");
  __builtin_amdgcn_s_barrier();
  compute((NT - 1) & 3);

  float tau_eta = 0.f, lssq = 0.f;
  if constexpr (MODE == 3) tau_eta = 0.5f * 0.8f / (1.0f + 0.1f * (float)stepi[0]);
  #pragma unroll
  for (int m = 0; m < 4; ++m) {
    #pragma unroll
    for (int n = 0; n < 4; ++n) {
      #pragma unroll
      for (int r = 0; r < 4; ++r) {
        int row = m0 + qr + 16 * m + 4 * g + r;   // C/D: col=lane&15, row=4*(lane>>4)+reg
        int col = n0 + qc + 16 * n + lr;
        size_t idx = (size_t)row * D + col;
        float v = acc[m][n][r];
        if constexpr (MODE == 1) {
          out16[idx] = f2bf(bf2f(b16a[idx]) - (v + f32b[col]));
        } else if constexpr (MODE == 2) {
          out16[idx] = f2bf(v * bf2f(b16a[idx]));
        } else {
          float dv = tau_eta * (v + bf2f(b16a[idx]) + bf2f(b16b[idx]));
          out16[idx] = f2bf(dv);
          lssq += dv * dv;
        }
      }
    }
  }
  if constexpr (MODE == 3) {
    lssq = wsumf(lssq);
    if (lane == 0) atomicAdd(ssq, lssq);
  }
}

// ---------------------------------------------------------------- final scale+clamp
__global__ __launch_bounds__(256) void final_k(const float* __restrict__ x,
                                               const unsigned short* __restrict__ d16,
                                               float* __restrict__ out,
                                               const float* __restrict__ ssq)
{
  float nrm = sqrtf(*ssq);
  float s = nrm > 1.0f ? 1.0f / (nrm + 1e-8f) : 1.0f;
  size_t i = (size_t)blockIdx.x * 256 + threadIdx.x;   // 8 elems/thread
  short8 dv = *(const short8*)(d16 + i * 8);
  const float4* xq = (const float4*)(x + i * 8);
  float4 xa = xq[0], xb = xq[1];
  float4 oa, ob;
  oa.x = fminf(fmaxf(xa.x + s * bf2f((unsigned short)dv[0]), -5.f), 5.f);
  oa.y = fminf(fmaxf(xa.y + s * bf2f((unsigned short)dv[1]), -5.f), 5.f);
  oa.z = fminf(fmaxf(xa.z + s * bf2f((unsigned short)dv[2]), -5.f), 5.f);
  oa.w = fminf(fmaxf(xa.w + s * bf2f((unsigned short)dv[3]), -5.f), 5.f);
  ob.x = fminf(fmaxf(xb.x + s * bf2f((unsigned short)dv[4]), -5.f), 5.f);
  ob.y = fminf(fmaxf(xb.y + s * bf2f((unsigned short)dv[5]), -5.f), 5.f);
  ob.z = fminf(fmaxf(xb.z + s * bf2f((unsigned short)dv[6]), -5.f), 5.f);
  ob.w = fminf(fmaxf(xb.w + s * bf2f((unsigned short)dv[7]), -5.f), 5.f);
  float4* oq = (float4*)(out + i * 8);
  oq[0] = oa; oq[1] = ob;
}

// ---------------------------------------------------------------- launch
extern "C" void kernel_launch(void* const* d_in, const int* in_sizes, int n_in,
                              void* d_out, int out_size, void* d_ws, size_t ws_size,
                              hipStream_t stream) {
  const float* bu    = (const float*)d_in[0];
  const float* td    = (const float*)d_in[1];
  const float* x     = (const float*)d_in[2];
  const float* V     = (const float*)d_in[3];
  const float* b_in  = (const float*)d_in[4];
  const float* W     = (const float*)d_in[5];
  const float* bout  = (const float*)d_in[6];
  const float* L     = (const float*)d_in[7];
  const float* Lm    = (const float*)d_in[8];
  const int*   stepi = (const int*)d_in[9];
  float* dout = (float*)d_out;

  char* p = (char*)d_ws;
  size_t off = 0;
  auto take = [&](size_t bytes) -> void* {
    void* r = (void*)(p + off);
    off += (bytes + 255) & ~(size_t)255;
    return r;
  };
  float* ssq            = (float*)take(4);
  unsigned short* Wbt   = (unsigned short*)take((size_t)D * D * 2);
  unsigned short* Wb2   = (unsigned short*)take((size_t)D * D * 2);
  unsigned short* Vbt   = (unsigned short*)take((size_t)D * D * 2);
  float* Mc7            = (float*)take((size_t)7 * D * 4);
  const size_t bd = (size_t)BATCH * D * 2;
  unsigned short* phi16 = (unsigned short*)take(bd);
  unsigned short* bu16  = (unsigned short*)take(bd);
  unsigned short* pd16  = (unsigned short*)take(bd);
  unsigned short* bse16 = (unsigned short*)take(bd);
  unsigned short* err16 = (unsigned short*)take(bd);
  unsigned short* fb16  = phi16;   // phi dead after G1; reuse for fb
  unsigned short* d16   = err16;   // err dead after G2; reuse for d

  prep_k<<<(D * D) / 256, 256, 0, stream>>>(W, V, L, Lm, Wbt, Wb2, Vbt, Mc7, ssq);
  kwta_k<<<BATCH / 4, 256, 0, stream>>>(x, td, bu, b_in, Mc7, phi16, pd16, bse16, bu16);
  gemm_k<1><<<(BATCH / 128) * (D / 128), 256, 0, stream>>>(
      phi16, Wbt, bout, bu16, nullptr, err16, nullptr, nullptr);
  gemm_k<2><<<(BATCH / 128) * (D / 128), 256, 0, stream>>>(
      err16, Wb2, nullptr, pd16, nullptr, fb16, nullptr, nullptr);
  gemm_k<3><<<(BATCH / 128) * (D / 128), 256, 0, stream>>>(
      bu16, Vbt, nullptr, fb16, bse16, d16, ssq, stepi);
  final_k<<<BATCH * D / 8 / 256, 256, 0, stream>>>(x, d16, dout, ssq);
}